// Round 1
// baseline (17.061 us; speedup 1.0000x reference)
//
#include <hip/hip_runtime.h>

#define VOCAB 32000
#define DIM   1024
#define SEQ_  2048
#define NBAT  4

__global__ __launch_bounds__(256) void verse_embed_ln_kernel(
    const int*   __restrict__ token_ids,    // [B,S]
    const int*   __restrict__ verse_pos,    // [B,S]
    const int*   __restrict__ book_types,   // [B,S]
    const float* __restrict__ emb_table,    // [VOCAB,D]
    const float* __restrict__ book_table,   // [4,D]
    const float* __restrict__ gamma,        // [D]
    const float* __restrict__ beta,         // [D]
    float*       __restrict__ out)          // [B,S,D]
{
    const int row = blockIdx.x;           // 0 .. B*S-1
    const int s   = row & (SEQ_ - 1);
    const int tid = threadIdx.x;
    const int d0  = tid << 2;             // 4 elems / thread

    // scalar per-row metadata
    const int tok   = token_ids[row];
    const int bt    = book_types[row];
    const int v     = verse_pos[row];
    const int vprev = (s == 0) ? -1 : verse_pos[row - 1];
    // verse_positions is sorted per row (zeros first), so the "last nonzero
    // verse before s" is simply v[s-1] (or none if v[s-1]==0). Run-start:
    const float w = (v != 0 && v != vprev) ? 1.2f : 1.0f;

    // gather embedding + book rows (coalesced float4 within the 4KB row)
    const float4 e  = *reinterpret_cast<const float4*>(emb_table + (size_t)tok * DIM + d0);
    const float4 bk = *reinterpret_cast<const float4*>(book_table + (size_t)bt * DIM + d0);

    // sinusoidal PE on the fly:
    // div_term[k] = exp(2k * -ln(10000)/D) = exp2(2k * -log2(10000)/D)
    // col 2k -> sin(s*div_term[k]), col 2k+1 -> cos(s*div_term[k])
    const float C2 = -13.287712379549449f / 1024.0f;   // -log2(10000)/D
    const float sf = (float)s;
    const float f0 = exp2f(C2 * (float)d0);            // k = d0/2  -> 2k = d0
    const float f1 = exp2f(C2 * (float)(d0 + 2));      // k+1
    float s0, c0, s1, c1;
    __sincosf(sf * f0, &s0, &c0);
    __sincosf(sf * f1, &s1, &c1);

    const float SQD = 32.0f;                           // sqrt(1024)
    const float x0 = e.x * SQD + s0 * w + bk.x;
    const float x1 = e.y * SQD + c0 * w + bk.y;
    const float x2 = e.z * SQD + s1 * w + bk.z;
    const float x3 = e.w * SQD + c1 * w + bk.w;

    // block-wide mean/var over 1024 elems
    float sum = x0 + x1 + x2 + x3;
    float sq  = x0 * x0 + x1 * x1 + x2 * x2 + x3 * x3;
    #pragma unroll
    for (int off = 32; off >= 1; off >>= 1) {
        sum += __shfl_xor(sum, off, 64);
        sq  += __shfl_xor(sq,  off, 64);
    }
    __shared__ float lsum[4], lsq[4];
    const int wid = tid >> 6;
    if ((tid & 63) == 0) { lsum[wid] = sum; lsq[wid] = sq; }
    __syncthreads();
    const float tsum = lsum[0] + lsum[1] + lsum[2] + lsum[3];
    const float tsq  = lsq[0]  + lsq[1]  + lsq[2]  + lsq[3];

    const float mean = tsum * (1.0f / (float)DIM);
    const float var  = tsq * (1.0f / (float)DIM) - mean * mean;
    const float rstd = rsqrtf(var + 1e-5f);

    const float4 g  = *reinterpret_cast<const float4*>(gamma + d0);
    const float4 bb = *reinterpret_cast<const float4*>(beta + d0);

    float4 o;
    o.x = (x0 - mean) * rstd * g.x + bb.x;
    o.y = (x1 - mean) * rstd * g.y + bb.y;
    o.z = (x2 - mean) * rstd * g.z + bb.z;
    o.w = (x3 - mean) * rstd * g.w + bb.w;
    *reinterpret_cast<float4*>(out + (size_t)row * DIM + d0) = o;
}

extern "C" void kernel_launch(void* const* d_in, const int* in_sizes, int n_in,
                              void* d_out, int out_size, void* d_ws, size_t ws_size,
                              hipStream_t stream) {
    const int*   token_ids  = (const int*)d_in[0];
    const int*   verse_pos  = (const int*)d_in[1];
    const int*   book_types = (const int*)d_in[2];
    const float* emb_table  = (const float*)d_in[3];
    const float* book_table = (const float*)d_in[4];
    const float* ln_gamma   = (const float*)d_in[5];
    const float* ln_beta    = (const float*)d_in[6];
    float* out = (float*)d_out;

    dim3 grid(NBAT * SEQ_);
    dim3 block(256);
    verse_embed_ln_kernel<<<grid, block, 0, stream>>>(
        token_ids, verse_pos, book_types, emb_table, book_table,
        ln_gamma, ln_beta, out);
}

// Round 2
// 16.511 us; speedup vs baseline: 1.0333x; 1.0333x over previous
//
#include <hip/hip_runtime.h>

#define VOCAB 32000
#define DIM   1024
#define SEQ_  2048
#define NBAT  4

// One 64-lane wave per row; each lane owns 16 elements as 4 coalesced
// float4 chunks at d = c*256 + lane*4. No LDS, no __syncthreads:
// the LayerNorm reduction is a pure in-wave shuffle butterfly.
__global__ __launch_bounds__(256) void verse_embed_ln_kernel(
    const int*   __restrict__ token_ids,    // [B,S]
    const int*   __restrict__ verse_pos,    // [B,S]
    const int*   __restrict__ book_types,   // [B,S]
    const float* __restrict__ emb_table,    // [VOCAB,D]
    const float* __restrict__ book_table,   // [4,D]
    const float* __restrict__ gamma,        // [D]
    const float* __restrict__ beta,         // [D]
    float*       __restrict__ out)          // [B,S,D]
{
    const int wid  = threadIdx.x >> 6;
    const int lane = threadIdx.x & 63;
    const int row  = (blockIdx.x << 2) + wid;   // 0 .. B*S-1
    const int s    = row & (SEQ_ - 1);

    // per-row scalar metadata (wave-uniform -> scalar loads)
    const int tok   = token_ids[row];
    const int bt    = book_types[row];
    const int v     = verse_pos[row];
    const int vprev = (s == 0) ? -1 : verse_pos[row - 1];
    // verse_positions sorted per row (zeros first) => run-start test is local
    const float w = (v != 0 && v != vprev) ? 1.2f : 1.0f;

    const float* __restrict__ erow = emb_table  + (size_t)tok * DIM;
    const float* __restrict__ brow = book_table + (size_t)bt  * DIM;

    // Issue all 8 gathers up front for max memory-level parallelism.
    float4 e[4], bk[4];
    #pragma unroll
    for (int c = 0; c < 4; ++c) {
        const int d0 = (c << 8) + (lane << 2);
        e[c]  = *reinterpret_cast<const float4*>(erow + d0);
        bk[c] = *reinterpret_cast<const float4*>(brow + d0);
    }

    const float C2  = -13.287712379549449f / 1024.0f;   // -log2(10000)/D
    const float sf  = (float)s;
    const float SQD = 32.0f;                             // sqrt(1024)

    float x[16];
    float sum = 0.0f, sq = 0.0f;
    #pragma unroll
    for (int c = 0; c < 4; ++c) {
        const int d0 = (c << 8) + (lane << 2);
        const float f0 = exp2f(C2 * (float)d0);
        const float f1 = exp2f(C2 * (float)(d0 + 2));
        float s0, c0, s1, c1;
        __sincosf(sf * f0, &s0, &c0);
        __sincosf(sf * f1, &s1, &c1);
        const float x0 = e[c].x * SQD + s0 * w + bk[c].x;
        const float x1 = e[c].y * SQD + c0 * w + bk[c].y;
        const float x2 = e[c].z * SQD + s1 * w + bk[c].z;
        const float x3 = e[c].w * SQD + c1 * w + bk[c].w;
        x[4 * c + 0] = x0; x[4 * c + 1] = x1; x[4 * c + 2] = x2; x[4 * c + 3] = x3;
        sum += (x0 + x1) + (x2 + x3);
        sq  += (x0 * x0 + x1 * x1) + (x2 * x2 + x3 * x3);
    }

    // in-wave butterfly reduction over 64 lanes
    #pragma unroll
    for (int off = 32; off >= 1; off >>= 1) {
        sum += __shfl_xor(sum, off, 64);
        sq  += __shfl_xor(sq,  off, 64);
    }

    const float mean = sum * (1.0f / (float)DIM);
    const float var  = sq * (1.0f / (float)DIM) - mean * mean;
    const float rstd = rsqrtf(var + 1e-5f);

    float* __restrict__ orow = out + (size_t)row * DIM;
    #pragma unroll
    for (int c = 0; c < 4; ++c) {
        const int d0 = (c << 8) + (lane << 2);
        const float4 g  = *reinterpret_cast<const float4*>(gamma + d0);
        const float4 bb = *reinterpret_cast<const float4*>(beta  + d0);
        float4 o;
        o.x = (x[4 * c + 0] - mean) * rstd * g.x + bb.x;
        o.y = (x[4 * c + 1] - mean) * rstd * g.y + bb.y;
        o.z = (x[4 * c + 2] - mean) * rstd * g.z + bb.z;
        o.w = (x[4 * c + 3] - mean) * rstd * g.w + bb.w;
        *reinterpret_cast<float4*>(orow + d0) = o;
    }
}

extern "C" void kernel_launch(void* const* d_in, const int* in_sizes, int n_in,
                              void* d_out, int out_size, void* d_ws, size_t ws_size,
                              hipStream_t stream) {
    const int*   token_ids  = (const int*)d_in[0];
    const int*   verse_pos  = (const int*)d_in[1];
    const int*   book_types = (const int*)d_in[2];
    const float* emb_table  = (const float*)d_in[3];
    const float* book_table = (const float*)d_in[4];
    const float* ln_gamma   = (const float*)d_in[5];
    const float* ln_beta    = (const float*)d_in[6];
    float* out = (float*)d_out;

    dim3 grid((NBAT * SEQ_) / 4);   // one wave per row, 4 rows per 256-thread block
    dim3 block(256);
    verse_embed_ln_kernel<<<grid, block, 0, stream>>>(
        token_ids, verse_pos, book_types, emb_table, book_table,
        ln_gamma, ln_beta, out);
}

// Round 3
// 16.356 us; speedup vs baseline: 1.0431x; 1.0095x over previous
//
#include <hip/hip_runtime.h>

#define DIM   1024
#define SEQ_  2048
#define NBAT  4

// One 64-lane wave per row. Lane owns d = c*256 + lane*4, c = 0..3.
// x[] lives in LDS (own-wave, no barrier) to keep VGPRs under the
// 6-waves/EU cap; the 4 embedding float4 gathers are staged up front
// for memory-level parallelism against L3 latency.
__global__ __launch_bounds__(256, 6) void verse_embed_ln_kernel(
    const int*   __restrict__ token_ids,    // [B,S]
    const int*   __restrict__ verse_pos,    // [B,S]
    const int*   __restrict__ book_types,   // [B,S]
    const float* __restrict__ emb_table,    // [VOCAB,D]
    const float* __restrict__ book_table,   // [4,D]
    const float* __restrict__ gamma,        // [D]
    const float* __restrict__ beta,         // [D]
    float*       __restrict__ out)          // [B,S,D]
{
    __shared__ float4 xs[4][4][64];         // [wave][chunk][lane], 16 KB/block

    const int wid  = threadIdx.x >> 6;
    const int lane = threadIdx.x & 63;
    const int row  = (blockIdx.x << 2) + wid;   // 0 .. B*S-1
    const int s    = row & (SEQ_ - 1);

    // wave-uniform per-row metadata (scalarized by compiler)
    const int tok   = token_ids[row];
    const int bt    = book_types[row];
    const int v     = verse_pos[row];
    const int vprev = (s == 0) ? -1 : verse_pos[row - 1];
    // verse_positions sorted per row (zeros first) => run-start test is local
    const float w = (v != 0 && v != vprev) ? 1.2f : 1.0f;

    const float* __restrict__ erow = emb_table  + (size_t)tok * DIM;
    const float* __restrict__ brow = book_table + (size_t)bt  * DIM;
    const int dl = lane << 2;

    // stage the 4 coalesced 1KB gathers (the only L3-latency loads)
    const float4 e0 = *reinterpret_cast<const float4*>(erow + dl);
    const float4 e1 = *reinterpret_cast<const float4*>(erow + 256 + dl);
    const float4 e2 = *reinterpret_cast<const float4*>(erow + 512 + dl);
    const float4 e3 = *reinterpret_cast<const float4*>(erow + 768 + dl);

    // frequencies: f(d) = 10000^(-d/1024); f(d+2) = f(d)*K2; f(d+256) = f(d)*0.1
    const float C2 = -13.287712379549449f / 1024.0f;   // -log2(10000)/D
    const float K2 = 0.9821718931198913f;              // 10000^(-1/512)
    const float sf = (float)s;
    float fbase = exp2f(C2 * (float)dl);               // one exp2 per lane
    const float SQD = 32.0f;                           // sqrt(1024)

    float sum = 0.0f, sq = 0.0f;
    const float4 eops[4] = {e0, e1, e2, e3};
    #pragma unroll
    for (int c = 0; c < 4; ++c) {
        const int d0 = (c << 8) + dl;
        const float4 bk = *reinterpret_cast<const float4*>(brow + d0); // L1-resident (16 KB table)
        const float a0 = sf * fbase;
        const float a1 = sf * (fbase * K2);
        const float s0 = __sinf(a0), c0 = __cosf(a0);
        const float s1 = __sinf(a1), c1 = __cosf(a1);
        fbase *= 0.1f;

        float4 x;
        x.x = eops[c].x * SQD + s0 * w + bk.x;
        x.y = eops[c].y * SQD + c0 * w + bk.y;
        x.z = eops[c].z * SQD + s1 * w + bk.z;
        x.w = eops[c].w * SQD + c1 * w + bk.w;
        xs[wid][c][lane] = x;

        sum += (x.x + x.y) + (x.z + x.w);
        sq  += (x.x * x.x + x.y * x.y) + (x.z * x.z + x.w * x.w);
    }

    // in-wave butterfly reduction over 64 lanes (no barrier needed)
    #pragma unroll
    for (int off = 32; off >= 1; off >>= 1) {
        sum += __shfl_xor(sum, off, 64);
        sq  += __shfl_xor(sq,  off, 64);
    }

    const float mean = sum * (1.0f / (float)DIM);
    const float var  = sq * (1.0f / (float)DIM) - mean * mean;
    const float rstd = rsqrtf(var + 1e-5f);

    float* __restrict__ orow = out + (size_t)row * DIM;
    #pragma unroll
    for (int c = 0; c < 4; ++c) {
        const int d0 = (c << 8) + dl;
        const float4 g  = *reinterpret_cast<const float4*>(gamma + d0);  // L1-resident
        const float4 bb = *reinterpret_cast<const float4*>(beta  + d0);  // L1-resident
        const float4 x  = xs[wid][c][lane];
        float4 o;
        o.x = (x.x - mean) * rstd * g.x + bb.x;
        o.y = (x.y - mean) * rstd * g.y + bb.y;
        o.z = (x.z - mean) * rstd * g.z + bb.z;
        o.w = (x.w - mean) * rstd * g.w + bb.w;
        *reinterpret_cast<float4*>(orow + d0) = o;
    }
}

extern "C" void kernel_launch(void* const* d_in, const int* in_sizes, int n_in,
                              void* d_out, int out_size, void* d_ws, size_t ws_size,
                              hipStream_t stream) {
    const int*   token_ids  = (const int*)d_in[0];
    const int*   verse_pos  = (const int*)d_in[1];
    const int*   book_types = (const int*)d_in[2];
    const float* emb_table  = (const float*)d_in[3];
    const float* book_table = (const float*)d_in[4];
    const float* ln_gamma   = (const float*)d_in[5];
    const float* ln_beta    = (const float*)d_in[6];
    float* out = (float*)d_out;

    dim3 grid((NBAT * SEQ_) / 4);   // one wave per row, 4 rows per 256-thread block
    dim3 block(256);
    verse_embed_ln_kernel<<<grid, block, 0, stream>>>(
        token_ids, verse_pos, book_types, emb_table, book_table,
        ln_gamma, ln_beta, out);
}